// Round 1
// baseline (227.914 us; speedup 1.0000x reference)
//
#include <hip/hip_runtime.h>

// out[s,a] = values[index[s,a]]
// index: 16384*2048 int32 (128 MiB), values: 100 fp32 (400 B), out: fp32 (128 MiB)
// Pure HBM-streaming gather. values staged in LDS; int4/float4 vectorized.

constexpr int VOCAB = 100;

__global__ __launch_bounds__(256) void gather_kernel(
    const int4* __restrict__ idx4,
    const float* __restrict__ vals,
    float4* __restrict__ out4,
    long long n4)
{
    __shared__ float svals[VOCAB];
    if (threadIdx.x < VOCAB) svals[threadIdx.x] = vals[threadIdx.x];
    __syncthreads();

    long long tid    = (long long)blockIdx.x * blockDim.x + threadIdx.x;
    long long stride = (long long)gridDim.x * blockDim.x;

    for (long long i = tid; i < n4; i += stride) {
        int4 v = idx4[i];
        float4 o;
        o.x = svals[v.x];
        o.y = svals[v.y];
        o.z = svals[v.z];
        o.w = svals[v.w];
        out4[i] = o;
    }
}

extern "C" void kernel_launch(void* const* d_in, const int* in_sizes, int n_in,
                              void* d_out, int out_size, void* d_ws, size_t ws_size,
                              hipStream_t stream) {
    const int*   idx  = (const int*)d_in[0];     // 16384*2048 int32
    const float* vals = (const float*)d_in[1];   // 100 fp32
    float*       out  = (float*)d_out;           // 16384*2048 fp32

    long long n  = (long long)in_sizes[0];       // 33554432, divisible by 4
    long long n4 = n / 4;                        // 8388608

    const int block = 256;
    const int grid  = 8192;                      // grid-stride: 4 iters/thread

    gather_kernel<<<grid, block, 0, stream>>>(
        (const int4*)idx, vals, (float4*)out, n4);
}

// Round 3
// 227.863 us; speedup vs baseline: 1.0002x; 1.0002x over previous
//
#include <hip/hip_runtime.h>

// out[s,a] = values[index[s,a]]
// index: 16384*2048 int32 (128 MiB), values: 100 fp32 (400 B), out: fp32 (128 MiB)
// Pure HBM-streaming gather: ~268 MB traffic, floor ~43 us @ 6.3 TB/s.
// R3: ext_vector_type for nontemporal builtins (HIP_vector_type rejected);
//     4 independent batched loads/thread (Little's law) + nontemporal hints.

constexpr int VOCAB = 100;

typedef int   vint4   __attribute__((ext_vector_type(4)));
typedef float vfloat4 __attribute__((ext_vector_type(4)));

__global__ __launch_bounds__(256) void gather_kernel(
    const vint4* __restrict__ idx4,
    const float* __restrict__ vals,
    vfloat4* __restrict__ out4,
    int n4)
{
    __shared__ float svals[VOCAB];
    if (threadIdx.x < VOCAB) svals[threadIdx.x] = vals[threadIdx.x];
    __syncthreads();

    const int S   = gridDim.x * blockDim.x;          // total threads
    const int tid = blockIdx.x * blockDim.x + threadIdx.x;

    int t = tid;
    // Main: 4 independent, per-instruction-coalesced loads in flight per thread.
    for (; t + 3 * S < n4; t += 4 * S) {
        vint4 v0 = __builtin_nontemporal_load(&idx4[t]);
        vint4 v1 = __builtin_nontemporal_load(&idx4[t + S]);
        vint4 v2 = __builtin_nontemporal_load(&idx4[t + 2 * S]);
        vint4 v3 = __builtin_nontemporal_load(&idx4[t + 3 * S]);

        vfloat4 o0 = { svals[v0.x], svals[v0.y], svals[v0.z], svals[v0.w] };
        vfloat4 o1 = { svals[v1.x], svals[v1.y], svals[v1.z], svals[v1.w] };
        vfloat4 o2 = { svals[v2.x], svals[v2.y], svals[v2.z], svals[v2.w] };
        vfloat4 o3 = { svals[v3.x], svals[v3.y], svals[v3.z], svals[v3.w] };

        __builtin_nontemporal_store(o0, &out4[t]);
        __builtin_nontemporal_store(o1, &out4[t + S]);
        __builtin_nontemporal_store(o2, &out4[t + 2 * S]);
        __builtin_nontemporal_store(o3, &out4[t + 3 * S]);
    }
    // Tail (not executed for the benchmark shape: n4 = 8388608 = 4*S exactly).
    for (; t < n4; t += S) {
        vint4 v = __builtin_nontemporal_load(&idx4[t]);
        vfloat4 o = { svals[v.x], svals[v.y], svals[v.z], svals[v.w] };
        __builtin_nontemporal_store(o, &out4[t]);
    }
}

extern "C" void kernel_launch(void* const* d_in, const int* in_sizes, int n_in,
                              void* d_out, int out_size, void* d_ws, size_t ws_size,
                              hipStream_t stream) {
    const int*   idx  = (const int*)d_in[0];     // 16384*2048 int32
    const float* vals = (const float*)d_in[1];   // 100 fp32
    float*       out  = (float*)d_out;           // fp32

    int n  = in_sizes[0];                        // 33554432 (divisible by 4)
    int n4 = n / 4;                              // 8388608

    const int block = 256;
    const int grid  = 8192;                      // 8192*256*4 vint4 == n4 exactly

    gather_kernel<<<grid, block, 0, stream>>>(
        (const vint4*)idx, vals, (vfloat4*)out, n4);
}

// Round 4
// 218.773 us; speedup vs baseline: 1.0418x; 1.0416x over previous
//
#include <hip/hip_runtime.h>

// out[s,a] = values[index[s,a]]
// index: 16384*2048 int32 (128 MiB), values: 100 fp32 (400 B), out: fp32 (128 MiB)
// Irreducible traffic: 268.4 MB -> 40-43 us floor @ 6.3-6.7 TB/s measured ceiling.
// R4 invariance probe: flat kernel, one int4->float4 per thread, no loop.
// R1 (1 load in flight) == R3 (4 in flight) == 227.9 us total => kernel is
// HBM-bound; residual is harness fills (ws-poison 512 MiB @ ~80 us, etc).

constexpr int VOCAB = 100;

typedef int   vint4   __attribute__((ext_vector_type(4)));
typedef float vfloat4 __attribute__((ext_vector_type(4)));

__global__ __launch_bounds__(256) void gather_kernel(
    const vint4* __restrict__ idx4,
    const float* __restrict__ vals,
    vfloat4* __restrict__ out4)
{
    __shared__ float svals[VOCAB];
    if (threadIdx.x < VOCAB) svals[threadIdx.x] = vals[threadIdx.x];
    __syncthreads();

    const int t = blockIdx.x * blockDim.x + threadIdx.x;  // one int4 per thread

    vint4 v = __builtin_nontemporal_load(&idx4[t]);
    vfloat4 o = { svals[v.x], svals[v.y], svals[v.z], svals[v.w] };
    __builtin_nontemporal_store(o, &out4[t]);
}

extern "C" void kernel_launch(void* const* d_in, const int* in_sizes, int n_in,
                              void* d_out, int out_size, void* d_ws, size_t ws_size,
                              hipStream_t stream) {
    const int*   idx  = (const int*)d_in[0];     // 16384*2048 int32
    const float* vals = (const float*)d_in[1];   // 100 fp32
    float*       out  = (float*)d_out;           // fp32

    int n  = in_sizes[0];                        // 33554432 (divisible by 4)
    int n4 = n / 4;                              // 8388608 = 32768 * 256

    const int block = 256;
    const int grid  = n4 / block;                // 32768 blocks, exact cover

    gather_kernel<<<grid, block, 0, stream>>>(
        (const vint4*)idx, vals, (vfloat4*)out);
}

// Round 5
// 217.251 us; speedup vs baseline: 1.0491x; 1.0070x over previous
//
#include <hip/hip_runtime.h>

// out[s,a] = values[index[s,a]]
// index: 16384*2048 int32 (128 MiB), values: 100 fp32 (400 B), out: fp32 (128 MiB)
// Irreducible traffic: 268.4 MB -> ~40 us floor @ 6.7 TB/s measured ceiling.
// R5: flat one-int4-per-thread (R4's win, -9us vs grid-stride), block=1024:
//     8192 WGs instead of 32768 -> 4x fewer dispatch prologues/barriers.

constexpr int VOCAB = 100;

typedef int   vint4   __attribute__((ext_vector_type(4)));
typedef float vfloat4 __attribute__((ext_vector_type(4)));

__global__ __launch_bounds__(1024) void gather_kernel(
    const vint4* __restrict__ idx4,
    const float* __restrict__ vals,
    vfloat4* __restrict__ out4)
{
    __shared__ float svals[VOCAB];
    if (threadIdx.x < VOCAB) svals[threadIdx.x] = vals[threadIdx.x];
    __syncthreads();

    const int t = blockIdx.x * blockDim.x + threadIdx.x;  // one int4 per thread

    vint4 v = __builtin_nontemporal_load(&idx4[t]);
    vfloat4 o = { svals[v.x], svals[v.y], svals[v.z], svals[v.w] };
    __builtin_nontemporal_store(o, &out4[t]);
}

extern "C" void kernel_launch(void* const* d_in, const int* in_sizes, int n_in,
                              void* d_out, int out_size, void* d_ws, size_t ws_size,
                              hipStream_t stream) {
    const int*   idx  = (const int*)d_in[0];     // 16384*2048 int32
    const float* vals = (const float*)d_in[1];   // 100 fp32
    float*       out  = (float*)d_out;           // fp32

    int n  = in_sizes[0];                        // 33554432 (divisible by 4)
    int n4 = n / 4;                              // 8388608 = 8192 * 1024

    const int block = 1024;
    const int grid  = n4 / block;                // 8192 blocks, exact cover

    gather_kernel<<<grid, block, 0, stream>>>(
        (const vint4*)idx, vals, (vfloat4*)out);
}